// Round 13
// baseline (115.525 us; speedup 1.0000x reference)
//
#include <hip/hip_runtime.h>

#define N_NODES 100000
#define N_EDGES 3200000
#define DIN     128
#define DOUT    64
#define GEMM_BLOCKS 1563   /* ceil(100000/64) */
#define RP_BLOCKS   12500  /* 3.2M/256 */
#define RPW 13             /* rows per persistent wave */

typedef unsigned short bf16_t;
typedef float f32x4  __attribute__((ext_vector_type(4)));
typedef short bf16x8 __attribute__((ext_vector_type(8)));

__device__ __forceinline__ bf16_t f32_to_bf16(float f) {
    union { float f; unsigned int u; } un; un.f = f;
    unsigned int u = un.u + 0x7fffu + ((un.u >> 16) & 1u);  // RNE
    return (bf16_t)(u >> 16);
}
__device__ __forceinline__ unsigned int pack2(float lo, float hi) {
    return (unsigned int)f32_to_bf16(lo) | ((unsigned int)f32_to_bf16(hi) << 16);
}
__device__ __forceinline__ float2 bf16x2_to_f32x2(unsigned int p) {
    union { unsigned int u; float f; } lo, hi;
    lo.u = p << 16;
    hi.u = p & 0xffff0000u;
    return make_float2(lo.f, hi.f);
}

#define UNPACK_FMA(ACC, G, VV)                                    \
    do {                                                          \
        const float2 _f0 = bf16x2_to_f32x2((G).x);                \
        const float2 _f1 = bf16x2_to_f32x2((G).y);                \
        const float2 _f2 = bf16x2_to_f32x2((G).z);                \
        const float2 _f3 = bf16x2_to_f32x2((G).w);                \
        ACC[0] += (VV) * _f0.x; ACC[1] += (VV) * _f0.y;           \
        ACC[2] += (VV) * _f1.x; ACC[3] += (VV) * _f1.y;           \
        ACC[4] += (VV) * _f2.x; ACC[5] += (VV) * _f2.y;           \
        ACC[6] += (VV) * _f3.x; ACC[7] += (VV) * _f3.y;           \
    } while (0)

// one masked 8-edge group (dead slots: clamp to start, v=0); requires start<end
#define MASKED_GROUP(ACC, EBASE)                                            \
    do {                                                                    \
        const int   _ei = (EBASE) + grp;                                    \
        const bool  _ok = _ei < end;                                        \
        const int   _ec = _ok ? _ei : start;                                \
        const int   _cc = cols[_ec];                                        \
        const float _vv = _ok ? vals[_ec] : 0.f;                            \
        const uint4 _g  = *(const uint4*)&xwb[(size_t)_cc * DOUT + 8 * fq]; \
        UNPACK_FMA(ACC, _g, _vv);                                           \
    } while (0)

// ---------------------------------------------------------------------------
// Kernel 1 (heterogeneous grid): blocks [0, GEMM_BLOCKS) = bf16 MFMA GEMM
// xw_bf16 = bf16(x @ W), layout xwb[node*64+f];
// blocks [GEMM_BLOCKS, +RP_BLOCKS) build row_ptr from the sorted rows array.
// ---------------------------------------------------------------------------
__global__ __launch_bounds__(256) void gemm_rowptr(const float* __restrict__ x,
                                                   const float* __restrict__ w,
                                                   const int*   __restrict__ rows,
                                                   bf16_t* __restrict__ xwb,
                                                   int* __restrict__ row_ptr) {
    __shared__ unsigned short Xs[64][DIN];  // 16 KB bf16, chunk-swizzled
    __shared__ unsigned short Wt[DOUT][DIN];// 16 KB bf16, W transposed, swizzled

    const int bid = blockIdx.x;
    const int tid = threadIdx.x;

    if (bid >= GEMM_BLOCKS) {
        const int e = (bid - GEMM_BLOCKS) * 256 + tid;
        if (e < N_EDGES) {
            const int cur  = rows[e];
            const int prev = (e == 0) ? -1 : rows[e - 1];
            for (int r = prev + 1; r <= cur; ++r) row_ptr[r] = e;
            if (e == N_EDGES - 1)
                for (int r = cur + 1; r <= N_NODES; ++r) row_ptr[r] = N_EDGES;
        }
        return;
    }

    const int block_row = bid * 64;

    {
        const float4* w4 = (const float4*)w;
#pragma unroll
        for (int i = 0; i < 8; ++i) {
            const int f4 = i * 256 + tid;       // 0..2047
            const float4 v = w4[f4];
            const int base = f4 * 4;
            const int k = base >> 6;            // row of W
            const int n = base & 63;            // col (multiple of 4)
            Wt[n + 0][(((k >> 3) ^ ((n + 0) & 7)) << 3) | (k & 7)] = f32_to_bf16(v.x);
            Wt[n + 1][(((k >> 3) ^ ((n + 1) & 7)) << 3) | (k & 7)] = f32_to_bf16(v.y);
            Wt[n + 2][(((k >> 3) ^ ((n + 2) & 7)) << 3) | (k & 7)] = f32_to_bf16(v.z);
            Wt[n + 3][(((k >> 3) ^ ((n + 3) & 7)) << 3) | (k & 7)] = f32_to_bf16(v.w);
        }
    }
    {
        const int r = tid >> 2;
        const int q = tid & 3;
        const int gr = block_row + r;
        const float4* xp = (const float4*)&x[(size_t)gr * DIN + q * 32];
        const bool ok = gr < N_NODES;
#pragma unroll
        for (int ci = 0; ci < 4; ++ci) {
            float4 a = make_float4(0.f, 0.f, 0.f, 0.f), b = a;
            if (ok) { a = xp[2 * ci]; b = xp[2 * ci + 1]; }
            uint4 pk;
            pk.x = pack2(a.x, a.y);
            pk.y = pack2(a.z, a.w);
            pk.z = pack2(b.x, b.y);
            pk.w = pack2(b.z, b.w);
            const int c = q * 4 + ci;
            *(uint4*)&Xs[r][(c ^ (r & 7)) << 3] = pk;
        }
    }
    __syncthreads();

    const int wv_ = tid >> 6;
    const int l   = tid & 63;
    const int lr  = l & 15;
    const int hi  = l >> 4;
    const int arow = wv_ * 16 + lr;

    f32x4 acc0 = {0.f, 0.f, 0.f, 0.f};
    f32x4 acc1 = acc0, acc2 = acc0, acc3 = acc0;
#pragma unroll
    for (int s = 0; s < 4; ++s) {
        const int kc = s * 4 + hi;
        const bf16x8 a  = *(const bf16x8*)&Xs[arow][(kc ^ (arow & 7)) << 3];
        const int bc = (kc ^ (lr & 7)) << 3;
        const bf16x8 b0 = *(const bf16x8*)&Wt[lr     ][bc];
        const bf16x8 b1 = *(const bf16x8*)&Wt[16 + lr][bc];
        const bf16x8 b2 = *(const bf16x8*)&Wt[32 + lr][bc];
        const bf16x8 b3 = *(const bf16x8*)&Wt[48 + lr][bc];
        acc0 = __builtin_amdgcn_mfma_f32_16x16x32_bf16(a, b0, acc0, 0, 0, 0);
        acc1 = __builtin_amdgcn_mfma_f32_16x16x32_bf16(a, b1, acc1, 0, 0, 0);
        acc2 = __builtin_amdgcn_mfma_f32_16x16x32_bf16(a, b2, acc2, 0, 0, 0);
        acc3 = __builtin_amdgcn_mfma_f32_16x16x32_bf16(a, b3, acc3, 0, 0, 0);
    }

#pragma unroll
    for (int reg = 0; reg < 4; ++reg) {
        const int grow = block_row + wv_ * 16 + hi * 4 + reg;
        if (grow < N_NODES) {
            bf16_t* o = &xwb[(size_t)grow * DOUT + lr];
            o[0]  = f32_to_bf16(acc0[reg]);
            o[16] = f32_to_bf16(acc1[reg]);
            o[32] = f32_to_bf16(acc2[reg]);
            o[48] = f32_to_bf16(acc3[reg]);
        }
    }
}

// ---------------------------------------------------------------------------
// Kernel 2: SpMM + combine, PERSISTENT waves. Each wave owns RPW contiguous
// rows; while processing row r it prefetches row r+1's row_ptr end and h0
// (row_ptr start is carried from the current row's end — zero extra loads).
// The prefetch loads stay in flight across the backedge (waitcnt counting),
// hiding the per-row serial chain. Inner geometry = R8 (best measured):
// grp = lane>>3 edge slot, fq = lane&7 feature octet, 4 unmasked octet
// gathers + masked-16 tail, butterfly reduce 8/16/32.
// ---------------------------------------------------------------------------
__global__ __launch_bounds__(256) void spmm_persist(const bf16_t* __restrict__ xwb,
                                                    const int*    __restrict__ row_ptr,
                                                    const int*    __restrict__ cols,
                                                    const float*  __restrict__ vals,
                                                    const float*  __restrict__ h0,
                                                    const float*  __restrict__ bias,
                                                    float* __restrict__ out) {
    const int wid  = (blockIdx.x * blockDim.x + threadIdx.x) >> 6;
    const int lane = threadIdx.x & 63;

    int r = wid * RPW;
    if (r >= N_NODES) return;
    const int rend = (r + RPW < N_NODES) ? (r + RPW) : N_NODES;

    const int grp = lane >> 3;
    const int fq  = lane & 7;

    const f32x4 ba = *(const f32x4*)&bias[8 * fq];
    const f32x4 bb = *(const f32x4*)&bias[8 * fq + 4];

    // prime the pipeline: row r's range + h0
    int sA = row_ptr[r];
    int eA = row_ptr[r + 1];
    f32x4 haA = __builtin_nontemporal_load((const f32x4*)&h0[(size_t)r * DOUT + 8 * fq]);
    f32x4 hbA = __builtin_nontemporal_load((const f32x4*)&h0[(size_t)r * DOUT + 8 * fq + 4]);

    for (;;) {
        // ---- prefetch next row (issued before current row's work) ----
        const int rn = r + 1;
        const bool more = rn < rend;
        int eN = 0;
        f32x4 haN = {0.f, 0.f, 0.f, 0.f}, hbN = haN;
        if (more) {
            eN  = row_ptr[rn + 1];                     // start of rn == eA (carried)
            haN = __builtin_nontemporal_load((const f32x4*)&h0[(size_t)rn * DOUT + 8 * fq]);
            hbN = __builtin_nontemporal_load((const f32x4*)&h0[(size_t)rn * DOUT + 8 * fq + 4]);
        }

        // ---- process current row ----
        const int start = __builtin_amdgcn_readfirstlane(sA);
        const int end   = __builtin_amdgcn_readfirstlane(eA);

        float accA[8] = {};
        float accB[8] = {};
        if (start < end) {
            int e = start;
            for (; e + 32 <= end; e += 32) {
                const int   c0 = cols[e      + grp];
                const int   c1 = cols[e + 8  + grp];
                const int   c2 = cols[e + 16 + grp];
                const int   c3 = cols[e + 24 + grp];
                const float v0 = vals[e      + grp];
                const float v1 = vals[e + 8  + grp];
                const float v2 = vals[e + 16 + grp];
                const float v3 = vals[e + 24 + grp];
                const uint4 g0 = *(const uint4*)&xwb[(size_t)c0 * DOUT + 8 * fq];
                const uint4 g1 = *(const uint4*)&xwb[(size_t)c1 * DOUT + 8 * fq];
                const uint4 g2 = *(const uint4*)&xwb[(size_t)c2 * DOUT + 8 * fq];
                const uint4 g3 = *(const uint4*)&xwb[(size_t)c3 * DOUT + 8 * fq];
                UNPACK_FMA(accA, g0, v0);
                UNPACK_FMA(accB, g1, v1);
                UNPACK_FMA(accA, g2, v2);
                UNPACK_FMA(accB, g3, v3);
            }
            for (; e < end; e += 16) {
                MASKED_GROUP(accA, e);
                if (e + 8 < end) MASKED_GROUP(accB, e + 8);
            }
        }

        // butterfly reduce across the 8 edge-groups
        float s0, s1, s2, s3, s4, s5, s6, s7;
#define RED(SJ, J)                                       \
        do {                                             \
            float _t = accA[J] + accB[J];                \
            _t += __shfl_xor(_t, 8, 64);                 \
            _t += __shfl_xor(_t, 16, 64);                \
            _t += __shfl_xor(_t, 32, 64);                \
            SJ = _t;                                     \
        } while (0)
        RED(s0, 0); RED(s1, 1); RED(s2, 2); RED(s3, 3);
        RED(s4, 4); RED(s5, 5); RED(s6, 6); RED(s7, 7);
#undef RED

        if (grp == 0) {
            f32x4 ra, rb;
            ra.x = 0.9f * s0 + 0.1f * haA.x + ba.x;
            ra.y = 0.9f * s1 + 0.1f * haA.y + ba.y;
            ra.z = 0.9f * s2 + 0.1f * haA.z + ba.z;
            ra.w = 0.9f * s3 + 0.1f * haA.w + ba.w;
            rb.x = 0.9f * s4 + 0.1f * hbA.x + bb.x;
            rb.y = 0.9f * s5 + 0.1f * hbA.y + bb.y;
            rb.z = 0.9f * s6 + 0.1f * hbA.z + bb.z;
            rb.w = 0.9f * s7 + 0.1f * hbA.w + bb.w;
            __builtin_nontemporal_store(ra, (f32x4*)&out[(size_t)r * DOUT + 8 * fq]);
            __builtin_nontemporal_store(rb, (f32x4*)&out[(size_t)r * DOUT + 8 * fq + 4]);
        }

        if (!more) break;
        sA = eA;        // start of next row = end of current (carried, no load)
        eA = eN;
        haA = haN; hbA = hbN;
        r = rn;
    }
}

extern "C" void kernel_launch(void* const* d_in, const int* in_sizes, int n_in,
                              void* d_out, int out_size, void* d_ws, size_t ws_size,
                              hipStream_t stream) {
    const float* x    = (const float*)d_in[0];
    const int*   rows = (const int*)  d_in[1];
    const int*   cols = (const int*)  d_in[2];
    const float* vals = (const float*)d_in[3];
    const float* h0   = (const float*)d_in[4];
    const float* w    = (const float*)d_in[5];
    const float* bias = (const float*)d_in[6];
    float* out = (float*)d_out;

    bf16_t* xwb = (bf16_t*)d_ws;                         // N*DOUT bf16 = 12.8 MB
    const size_t xw_bytes = (size_t)N_NODES * DOUT * sizeof(bf16_t);
    int* row_ptr = (int*)((char*)d_ws + xw_bytes);       // (N+1) ints = 400 KB

    gemm_rowptr<<<GEMM_BLOCKS + RP_BLOCKS, 256, 0, stream>>>(x, w, rows, xwb, row_ptr);

    const int waves  = (N_NODES + RPW - 1) / RPW;        // 7693
    const int blocks = (waves + 3) / 4;                  // 4 waves / block
    spmm_persist<<<blocks, 256, 0, stream>>>(
        xwb, row_ptr, cols, vals, h0, bias, out);
}

// Round 14
// 90.116 us; speedup vs baseline: 1.2820x; 1.2820x over previous
//
#include <hip/hip_runtime.h>

#define N_NODES 100000
#define N_EDGES 3200000
#define DIN     128
#define DOUT    64
#define GEMM_BLOCKS 1563   /* ceil(100000/64) */
#define RP_BLOCKS   12500  /* 3.2M/256 */

typedef unsigned short bf16_t;
typedef float f32x4  __attribute__((ext_vector_type(4)));
typedef short bf16x8 __attribute__((ext_vector_type(8)));

__device__ __forceinline__ bf16_t f32_to_bf16(float f) {
    union { float f; unsigned int u; } un; un.f = f;
    unsigned int u = un.u + 0x7fffu + ((un.u >> 16) & 1u);  // RNE
    return (bf16_t)(u >> 16);
}
__device__ __forceinline__ unsigned int pack2(float lo, float hi) {
    return (unsigned int)f32_to_bf16(lo) | ((unsigned int)f32_to_bf16(hi) << 16);
}
__device__ __forceinline__ float2 bf16x2_to_f32x2(unsigned int p) {
    union { unsigned int u; float f; } lo, hi;
    lo.u = p << 16;
    hi.u = p & 0xffff0000u;
    return make_float2(lo.f, hi.f);
}

#define UNPACK_FMA(ACC, G, VV)                                    \
    do {                                                          \
        const float2 _f0 = bf16x2_to_f32x2((G).x);                \
        const float2 _f1 = bf16x2_to_f32x2((G).y);                \
        const float2 _f2 = bf16x2_to_f32x2((G).z);                \
        const float2 _f3 = bf16x2_to_f32x2((G).w);                \
        ACC[0] += (VV) * _f0.x; ACC[1] += (VV) * _f0.y;           \
        ACC[2] += (VV) * _f1.x; ACC[3] += (VV) * _f1.y;           \
        ACC[4] += (VV) * _f2.x; ACC[5] += (VV) * _f2.y;           \
        ACC[6] += (VV) * _f3.x; ACC[7] += (VV) * _f3.y;           \
    } while (0)

// one masked 8-edge group (dead slots clamp to start -> one shared line, v=0)
#define MASKED_GROUP(ACC, EBASE)                                            \
    do {                                                                    \
        const int   _ei = (EBASE) + grp;                                    \
        const bool  _ok = _ei < end;                                        \
        const int   _ec = _ok ? _ei : start;                                \
        const int   _cc = cols[_ec];                                        \
        const float _vv = _ok ? vals[_ec] : 0.f;                            \
        const uint4 _g  = *(const uint4*)&xwb[(size_t)_cc * DOUT + 8 * fq]; \
        UNPACK_FMA(ACC, _g, _vv);                                           \
    } while (0)

// ---------------------------------------------------------------------------
// Kernel 1 (heterogeneous grid): blocks [0, GEMM_BLOCKS) = bf16 MFMA GEMM
// xw_bf16 = bf16(x @ W), layout xwb[node*64+f];
// blocks [GEMM_BLOCKS, +RP_BLOCKS) build row_ptr from the sorted rows array.
// ---------------------------------------------------------------------------
__global__ __launch_bounds__(256) void gemm_rowptr(const float* __restrict__ x,
                                                   const float* __restrict__ w,
                                                   const int*   __restrict__ rows,
                                                   bf16_t* __restrict__ xwb,
                                                   int* __restrict__ row_ptr) {
    __shared__ unsigned short Xs[64][DIN];  // 16 KB bf16, chunk-swizzled
    __shared__ unsigned short Wt[DOUT][DIN];// 16 KB bf16, W transposed, swizzled

    const int bid = blockIdx.x;
    const int tid = threadIdx.x;

    if (bid >= GEMM_BLOCKS) {
        const int e = (bid - GEMM_BLOCKS) * 256 + tid;
        if (e < N_EDGES) {
            const int cur  = rows[e];
            const int prev = (e == 0) ? -1 : rows[e - 1];
            for (int r = prev + 1; r <= cur; ++r) row_ptr[r] = e;
            if (e == N_EDGES - 1)
                for (int r = cur + 1; r <= N_NODES; ++r) row_ptr[r] = N_EDGES;
        }
        return;
    }

    const int block_row = bid * 64;

    {
        const float4* w4 = (const float4*)w;
#pragma unroll
        for (int i = 0; i < 8; ++i) {
            const int f4 = i * 256 + tid;       // 0..2047
            const float4 v = w4[f4];
            const int base = f4 * 4;
            const int k = base >> 6;            // row of W
            const int n = base & 63;            // col (multiple of 4)
            Wt[n + 0][(((k >> 3) ^ ((n + 0) & 7)) << 3) | (k & 7)] = f32_to_bf16(v.x);
            Wt[n + 1][(((k >> 3) ^ ((n + 1) & 7)) << 3) | (k & 7)] = f32_to_bf16(v.y);
            Wt[n + 2][(((k >> 3) ^ ((n + 2) & 7)) << 3) | (k & 7)] = f32_to_bf16(v.z);
            Wt[n + 3][(((k >> 3) ^ ((n + 3) & 7)) << 3) | (k & 7)] = f32_to_bf16(v.w);
        }
    }
    {
        const int r = tid >> 2;
        const int q = tid & 3;
        const int gr = block_row + r;
        const float4* xp = (const float4*)&x[(size_t)gr * DIN + q * 32];
        const bool ok = gr < N_NODES;
#pragma unroll
        for (int ci = 0; ci < 4; ++ci) {
            float4 a = make_float4(0.f, 0.f, 0.f, 0.f), b = a;
            if (ok) { a = xp[2 * ci]; b = xp[2 * ci + 1]; }
            uint4 pk;
            pk.x = pack2(a.x, a.y);
            pk.y = pack2(a.z, a.w);
            pk.z = pack2(b.x, b.y);
            pk.w = pack2(b.z, b.w);
            const int c = q * 4 + ci;
            *(uint4*)&Xs[r][(c ^ (r & 7)) << 3] = pk;
        }
    }
    __syncthreads();

    const int wv_ = tid >> 6;
    const int l   = tid & 63;
    const int lr  = l & 15;
    const int hi  = l >> 4;
    const int arow = wv_ * 16 + lr;

    f32x4 acc0 = {0.f, 0.f, 0.f, 0.f};
    f32x4 acc1 = acc0, acc2 = acc0, acc3 = acc0;
#pragma unroll
    for (int s = 0; s < 4; ++s) {
        const int kc = s * 4 + hi;
        const bf16x8 a  = *(const bf16x8*)&Xs[arow][(kc ^ (arow & 7)) << 3];
        const int bc = (kc ^ (lr & 7)) << 3;
        const bf16x8 b0 = *(const bf16x8*)&Wt[lr     ][bc];
        const bf16x8 b1 = *(const bf16x8*)&Wt[16 + lr][bc];
        const bf16x8 b2 = *(const bf16x8*)&Wt[32 + lr][bc];
        const bf16x8 b3 = *(const bf16x8*)&Wt[48 + lr][bc];
        acc0 = __builtin_amdgcn_mfma_f32_16x16x32_bf16(a, b0, acc0, 0, 0, 0);
        acc1 = __builtin_amdgcn_mfma_f32_16x16x32_bf16(a, b1, acc1, 0, 0, 0);
        acc2 = __builtin_amdgcn_mfma_f32_16x16x32_bf16(a, b2, acc2, 0, 0, 0);
        acc3 = __builtin_amdgcn_mfma_f32_16x16x32_bf16(a, b3, acc3, 0, 0, 0);
    }

#pragma unroll
    for (int reg = 0; reg < 4; ++reg) {
        const int grow = block_row + wv_ * 16 + hi * 4 + reg;
        if (grow < N_NODES) {
            bf16_t* o = &xwb[(size_t)grow * DOUT + lr];
            o[0]  = f32_to_bf16(acc0[reg]);
            o[16] = f32_to_bf16(acc1[reg]);
            o[32] = f32_to_bf16(acc2[reg]);
            o[48] = f32_to_bf16(acc3[reg]);
        }
    }
}

// ---------------------------------------------------------------------------
// Kernel 2: SpMM + combine — R8's exact geometry (best measured: 71.6 us).
// One wave per row; grp = lane>>3 edge slot, fq = lane&7 feature octet; one
// dwordx4 gather covers 8 edges. Main loop: 32 edges = 4 independent
// octet-gathers in flight. Butterfly reduce (shfl_xor 8/16/32).
// ---------------------------------------------------------------------------
__global__ __launch_bounds__(256) void spmm_combine(const bf16_t* __restrict__ xwb,
                                                    const int*    __restrict__ row_ptr,
                                                    const int*    __restrict__ cols,
                                                    const float*  __restrict__ vals,
                                                    const float*  __restrict__ h0,
                                                    const float*  __restrict__ bias,
                                                    float* __restrict__ out) {
    const int wid  = (blockIdx.x * blockDim.x + threadIdx.x) >> 6;
    const int lane = threadIdx.x & 63;
    if (wid >= N_NODES) return;

    const int grp = lane >> 3;   // edge slot within group of 8
    const int fq  = lane & 7;    // feature octet index

    const int row   = __builtin_amdgcn_readfirstlane(wid);
    const int start = __builtin_amdgcn_readfirstlane(row_ptr[row]);
    const int end   = __builtin_amdgcn_readfirstlane(row_ptr[row + 1]);

    const f32x4 ha = __builtin_nontemporal_load((const f32x4*)&h0[(size_t)row * DOUT + 8 * fq]);
    const f32x4 hb = __builtin_nontemporal_load((const f32x4*)&h0[(size_t)row * DOUT + 8 * fq + 4]);
    const f32x4 ba = *(const f32x4*)&bias[8 * fq];
    const f32x4 bb = *(const f32x4*)&bias[8 * fq + 4];

    float accA[8] = {};
    float accB[8] = {};

    if (start < end) {
        int e = start;
        // main: 32 edges / iter = 4 independent octet-gathers in flight
        for (; e + 32 <= end; e += 32) {
            const int   c0 = cols[e      + grp];
            const int   c1 = cols[e + 8  + grp];
            const int   c2 = cols[e + 16 + grp];
            const int   c3 = cols[e + 24 + grp];
            const float v0 = vals[e      + grp];
            const float v1 = vals[e + 8  + grp];
            const float v2 = vals[e + 16 + grp];
            const float v3 = vals[e + 24 + grp];
            const uint4 g0 = *(const uint4*)&xwb[(size_t)c0 * DOUT + 8 * fq];
            const uint4 g1 = *(const uint4*)&xwb[(size_t)c1 * DOUT + 8 * fq];
            const uint4 g2 = *(const uint4*)&xwb[(size_t)c2 * DOUT + 8 * fq];
            const uint4 g3 = *(const uint4*)&xwb[(size_t)c3 * DOUT + 8 * fq];
            UNPACK_FMA(accA, g0, v0);
            UNPACK_FMA(accB, g1, v1);
            UNPACK_FMA(accA, g2, v2);
            UNPACK_FMA(accB, g3, v3);
        }
        // masked tail: 16 edges / iter (2 independent masked groups)
        for (; e < end; e += 16) {
            MASKED_GROUP(accA, e);
            if (e + 8 < end) MASKED_GROUP(accB, e + 8);
        }
    }

    // butterfly reduce across the 8 edge-groups
    float s0, s1, s2, s3, s4, s5, s6, s7;
#define RED(SJ, J)                                       \
    do {                                                 \
        float _t = accA[J] + accB[J];                    \
        _t += __shfl_xor(_t, 8, 64);                     \
        _t += __shfl_xor(_t, 16, 64);                    \
        _t += __shfl_xor(_t, 32, 64);                    \
        SJ = _t;                                         \
    } while (0)
    RED(s0, 0); RED(s1, 1); RED(s2, 2); RED(s3, 3);
    RED(s4, 4); RED(s5, 5); RED(s6, 6); RED(s7, 7);
#undef RED

    if (grp == 0) {
        f32x4 ra, rb;
        ra.x = 0.9f * s0 + 0.1f * ha.x + ba.x;
        ra.y = 0.9f * s1 + 0.1f * ha.y + ba.y;
        ra.z = 0.9f * s2 + 0.1f * ha.z + ba.z;
        ra.w = 0.9f * s3 + 0.1f * ha.w + ba.w;
        rb.x = 0.9f * s4 + 0.1f * hb.x + bb.x;
        rb.y = 0.9f * s5 + 0.1f * hb.y + bb.y;
        rb.z = 0.9f * s6 + 0.1f * hb.z + bb.z;
        rb.w = 0.9f * s7 + 0.1f * hb.w + bb.w;
        __builtin_nontemporal_store(ra, (f32x4*)&out[(size_t)row * DOUT + 8 * fq]);
        __builtin_nontemporal_store(rb, (f32x4*)&out[(size_t)row * DOUT + 8 * fq + 4]);
    }
}

extern "C" void kernel_launch(void* const* d_in, const int* in_sizes, int n_in,
                              void* d_out, int out_size, void* d_ws, size_t ws_size,
                              hipStream_t stream) {
    const float* x    = (const float*)d_in[0];
    const int*   rows = (const int*)  d_in[1];
    const int*   cols = (const int*)  d_in[2];
    const float* vals = (const float*)d_in[3];
    const float* h0   = (const float*)d_in[4];
    const float* w    = (const float*)d_in[5];
    const float* bias = (const float*)d_in[6];
    float* out = (float*)d_out;

    bf16_t* xwb = (bf16_t*)d_ws;                         // N*DOUT bf16 = 12.8 MB
    const size_t xw_bytes = (size_t)N_NODES * DOUT * sizeof(bf16_t);
    int* row_ptr = (int*)((char*)d_ws + xw_bytes);       // (N+1) ints = 400 KB

    gemm_rowptr<<<GEMM_BLOCKS + RP_BLOCKS, 256, 0, stream>>>(x, w, rows, xwb, row_ptr);
    spmm_combine<<<(N_NODES * 64 + 255) / 256, 256, 0, stream>>>(
        xwb, row_ptr, cols, vals, h0, bias, out);
}